// Round 1
// 537.918 us; speedup vs baseline: 1.1724x; 1.1724x over previous
//
#include <hip/hip_runtime.h>

// Instant-NGP 2D hashgrid (L=16, T=2^20, F=2, N_MIN=16, b=2) + MLP 32->128->128->3.
//
// Two-pass level-major restructure:
//   Pass 1 (ngp_encode): grid ordered level-major (16 levels x 1024 blocks).
//     HW dispatches blocks roughly in blockIdx order, so at any instant the
//     resident blocks hammer only 1-2 levels' tables (8-16 MiB hot set ->
//     fits aggregate L2, trivially fits L3) instead of all 128 MiB at once.
//     Table lines get their ~30x reuse while resident; HBM fetch collapses
//     to ~first-touch. Features stored as packed bf16 pairs (uint) in a
//     static 64 MB device buffer, level-major [L][N] for coalesced stores.
//   Pass 2 (ngp_mlp): previous harness-verified fused MLP, encode replaced
//     by 4 coalesced dword loads/lane from the feature buffer.
//
// mfma_f32_16x16x32_bf16 layouts (HW-verified per guide):
//   A[m][k]: m = lane&15, k = (lane>>4)*8 + j   (8 bf16 / lane)
//   B[k][n]: n = lane&15, k = (lane>>4)*8 + j
//   D[m][n]: n = lane&15, m = (lane>>4)*4 + r   (4 f32 / lane)

#define T_SIZE  (1u << 20)
#define HASH_Y  2654435761u
#define NLVL    16
#define MAXPTS  (1u << 20)

typedef __bf16 bf16x8 __attribute__((ext_vector_type(8)));
typedef float f32x4 __attribute__((ext_vector_type(4)));
typedef unsigned short u16x8 __attribute__((ext_vector_type(8)));
typedef unsigned short u16x4 __attribute__((ext_vector_type(4)));

// 64 MiB feature scratch: [level][point] packed {bf16 g0, bf16 g1}.
__device__ unsigned int g_feat[NLVL * MAXPTS];

static __device__ __forceinline__ unsigned short f2bf(float f) {
    union { float f; unsigned u; } v; v.f = f;
    unsigned u = v.u;
    u += 0x7fffu + ((u >> 16) & 1u);   // round-to-nearest-even
    return (unsigned short)(u >> 16);
}

static __device__ __forceinline__ f32x4 mfma16(u16x8 a, u16x8 b, f32x4 c) {
    return __builtin_amdgcn_mfma_f32_16x16x32_bf16(
        __builtin_bit_cast(bf16x8, a), __builtin_bit_cast(bf16x8, b), c, 0, 0, 0);
}

// ---------------- Pass 1: level-major hashgrid encode ----------------
// blockIdx = lvl * bpl + blk; each block encodes 1024 consecutive points at
// one level; each thread does 4 consecutive points (uint4 feature store).
__global__ __launch_bounds__(256)
void ngp_encode(const float* __restrict__ uv, const float* __restrict__ tables,
                int npts, int bpl)
{
    const int bid = blockIdx.x;
    const int lvl = bid / bpl;               // scalar div, once per block
    const int blk = bid - lvl * bpl;
    const int base = (blk << 10) + (threadIdx.x << 2);
    if (base >= npts) return;

    const unsigned res = 16u << lvl;
    const float fres = (float)res;
    const unsigned rp1 = res + 1u;
    const unsigned mask = T_SIZE - 1u;
    const bool dense = lvl < 6;              // (res+1)^2 <= T  <=>  lvl <= 5
    const float2* __restrict__ t2 = (const float2*)tables + (size_t)lvl * T_SIZE;

    // uv for 4 consecutive points: 32 B, two float4 loads.
    const float4* u4 = (const float4*)(uv + (size_t)base * 2);
    float4 ua = u4[0], ub = u4[1];
    float2 pts[4] = { {ua.x, ua.y}, {ua.z, ua.w}, {ub.x, ub.y}, {ub.z, ub.w} };

    unsigned pk[4];
#pragma unroll
    for (int u = 0; u < 4; ++u) {
        float px = pts[u].x * fres, py = pts[u].y * fres;
        float fx = floorf(px), fy = floorf(py);
        float wx = px - fx, wy = py - fy;
        unsigned cx = (unsigned)fx, cy = (unsigned)fy;
        unsigned hy0 = cy * HASH_Y, hy1 = (cy + 1u) * HASH_Y;
        unsigned i00 = dense ? (cx + cy * rp1)              : ((cx ^ hy0) & mask);
        unsigned i01 = dense ? (cx + (cy + 1u) * rp1)       : ((cx ^ hy1) & mask);
        unsigned i10 = dense ? (cx + 1u + cy * rp1)         : (((cx + 1u) ^ hy0) & mask);
        unsigned i11 = dense ? (cx + 1u + (cy + 1u) * rp1)  : (((cx + 1u) ^ hy1) & mask);
        float2 f00 = t2[i00], f01 = t2[i01], f10 = t2[i10], f11 = t2[i11];
        float w00 = (1.f - wx) * (1.f - wy);
        float w01 = (1.f - wx) * wy;
        float w10 = wx * (1.f - wy);
        float w11 = wx * wy;
        float g0 = w00 * f00.x + w01 * f01.x + w10 * f10.x + w11 * f11.x;
        float g1 = w00 * f00.y + w01 * f01.y + w10 * f10.y + w11 * f11.y;
        pk[u] = (unsigned)f2bf(g0) | ((unsigned)f2bf(g1) << 16);
    }
    *(uint4*)(g_feat + (size_t)lvl * npts + base) = make_uint4(pk[0], pk[1], pk[2], pk[3]);
}

// ---------------- Pass 2: fused MLP 32->128->128->3 ----------------
// LDS: w2T[out 128][in 136 pad] bf16 (34816 B) + h[4 waves][16 pts][136 pad]
// (17408 B) + biases (1024 B) = 53248 B < 64 KB WG limit; 3 blocks/CU.
__global__ __launch_bounds__(256, 2)
void ngp_mlp(const float* __restrict__ w1, const float* __restrict__ b1,
             const float* __restrict__ w2, const float* __restrict__ b2,
             const float* __restrict__ w3, const float* __restrict__ b3,
             float* __restrict__ out, int npts)
{
    __shared__ __align__(16) unsigned short w2T[128 * 136];
    __shared__ __align__(16) unsigned short hbuf[4 * 16 * 136];
    __shared__ float b1s[128], b2s[128];

    const int tid = threadIdx.x;
    for (int e = tid; e < 128 * 128; e += 256) {        // w2 is [in][out]; store w2T[out][in]
        int i = e >> 7, o = e & 127;
        w2T[o * 136 + i] = f2bf(w2[e]);
    }
    if (tid < 128) { b1s[tid] = b1[tid]; b2s[tid] = b2[tid]; }
    __syncthreads();

    const int lane = tid & 63;
    const int wv = tid >> 6;
    const int lanelo = lane & 15;
    const int quad = lane >> 4;

    // Register-resident A-fragments: layer 1 (w1^T [128x32]) and layer 3 (w3^T [3x128], rows 3..15 zero).
    u16x8 a1[8];
#pragma unroll
    for (int mt = 0; mt < 8; ++mt)
#pragma unroll
        for (int j = 0; j < 8; ++j)
            a1[mt][j] = f2bf(w1[(quad * 8 + j) * 128 + mt * 16 + lanelo]);  // w1[k][m]

    u16x8 a3[4];
#pragma unroll
    for (int ks = 0; ks < 4; ++ks)
#pragma unroll
        for (int j = 0; j < 8; ++j) {
            int k = ks * 32 + quad * 8 + j;
            a3[ks][j] = (lanelo < 3) ? f2bf(w3[k * 3 + lanelo]) : (unsigned short)0;  // w3[k][m]
        }

    const int NT = npts >> 4;                 // 16-point tiles
    const int nwaves = gridDim.x * 4;
    const int gwave = blockIdx.x * 4 + wv;
    const int niter = (NT + nwaves - 1) / nwaves;   // uniform trip count (syncthreads-safe)

    unsigned short* hp = hbuf + (wv * 16 + lanelo) * 136;   // this lane's point-row

    for (int it = 0; it < niter; ++it) {
        int tile = gwave + it * nwaves;
        bool act = tile < NT;
        int pt = (tile << 4) + lanelo;

        if (act) {
            // ---- B-fragment: this lane holds levels 4*quad..4*quad+3 of point pt ----
            u16x8 xb;
#pragma unroll
            for (int i = 0; i < 4; ++i) {
                unsigned fp = g_feat[(size_t)((quad << 2) + i) * npts + pt];
                xb[2 * i]     = (unsigned short)(fp & 0xffffu);
                xb[2 * i + 1] = (unsigned short)(fp >> 16);
            }
            // ---- layer 1: 8 MFMAs, K=32 in one shot ----
            f32x4 z = {0.f, 0.f, 0.f, 0.f};
            f32x4 d[8];
#pragma unroll
            for (int mt = 0; mt < 8; ++mt) d[mt] = mfma16(a1[mt], xb, z);
            // bias + relu + pack to LDS h[point][neuron]  (lane writes its own row, cols mt*16+quad*4..+3)
#pragma unroll
            for (int mt = 0; mt < 8; ++mt) {
                u16x4 pk;
#pragma unroll
                for (int r = 0; r < 4; ++r) {
                    float hv = d[mt][r] + b1s[mt * 16 + quad * 4 + r];
                    pk[r] = f2bf(fmaxf(hv, 0.f));
                }
                *(u16x4*)(hp + mt * 16 + quad * 4) = pk;
            }
        }
        __syncthreads();
        if (act) {
            // ---- layer 2: K=128 in 4 steps x 8 m-tiles ----
            f32x4 z = {0.f, 0.f, 0.f, 0.f};
            f32x4 e[8];
#pragma unroll
            for (int mt = 0; mt < 8; ++mt) e[mt] = z;
#pragma unroll
            for (int ks = 0; ks < 4; ++ks) {
                u16x8 bb = *(const u16x8*)(hp + ks * 32 + quad * 8);   // h1[pt][k..k+7]
#pragma unroll
                for (int mt = 0; mt < 8; ++mt) {
                    u16x8 aa = *(const u16x8*)(w2T + (mt * 16 + lanelo) * 136 + ks * 32 + quad * 8);
                    e[mt] = mfma16(aa, bb, e[mt]);
                }
            }
            // bias + relu + pack back to same LDS rows (all reads above precede these writes; DS in-order per wave)
#pragma unroll
            for (int mt = 0; mt < 8; ++mt) {
                u16x4 pk;
#pragma unroll
                for (int r = 0; r < 4; ++r) {
                    float hv = e[mt][r] + b2s[mt * 16 + quad * 4 + r];
                    pk[r] = f2bf(fmaxf(hv, 0.f));
                }
                *(u16x4*)(hp + mt * 16 + quad * 4) = pk;
            }
        }
        __syncthreads();
        if (act) {
            // ---- layer 3: 4 MFMAs, rows 0..2 = RGB logits ----
            f32x4 o3 = {0.f, 0.f, 0.f, 0.f};
#pragma unroll
            for (int ks = 0; ks < 4; ++ks) {
                u16x8 bb = *(const u16x8*)(hp + ks * 32 + quad * 8);
                o3 = mfma16(a3[ks], bb, o3);
            }
            if (quad == 0) {   // D rows quad*4+r -> rows 0..2 live in quad 0
                float* op = out + (size_t)pt * 3;
#pragma unroll
                for (int r = 0; r < 3; ++r) {
                    float lv = o3[r] + b3[r];
                    op[r] = 1.f / (1.f + expf(-lv));
                }
            }
        }
    }
}

extern "C" void kernel_launch(void* const* d_in, const int* in_sizes, int n_in,
                              void* d_out, int out_size, void* d_ws, size_t ws_size,
                              hipStream_t stream) {
    const float* uv     = (const float*)d_in[0];
    const float* tables = (const float*)d_in[1];
    const float* w1     = (const float*)d_in[2];
    const float* b1     = (const float*)d_in[3];
    const float* w2     = (const float*)d_in[4];
    const float* b2     = (const float*)d_in[5];
    const float* w3     = (const float*)d_in[6];
    const float* b3     = (const float*)d_in[7];
    float* out = (float*)d_out;
    int npts = in_sizes[0] / 2;          // uv is [N,2]

    // Pass 1: level-major encode. bpl blocks of 1024 points per level;
    // blockIdx ascending => levels hit the caches one after another.
    int bpl = (npts + 1023) >> 10;
    hipLaunchKernelGGL(ngp_encode, dim3(NLVL * bpl), dim3(256), 0, stream,
                       uv, tables, npts, bpl);

    // Pass 2: fused MLP. 2048 blocks x 4 waves = 8192 wave-slots.
    hipLaunchKernelGGL(ngp_mlp, dim3(2048), dim3(256), 0, stream,
                       w1, b1, w2, b2, w3, b3, out, npts);
}